// Round 1
// baseline (329.085 us; speedup 1.0000x reference)
//
#include <hip/hip_runtime.h>

// Chamfer distance L2: B=8, N=M=8192, fp32 3D points.
// d(q,p) = ||q||^2 + ||p||^2 - 2 q.p  (matches reference's expanded form).
// Pack each set as float4 (x, y, z, ||p||^2); per-thread q' = -2q, then
// inner loop is 3 fma + 1 min per pair with wave-uniform target loads
// (scalar-pipe s_load). Deterministic two-stage sum reduction.

constexpr int B  = 8;
constexpr int N  = 8192;          // points per batch (both sets)
constexpr int BN = B * N;         // 65536 points per set
constexpr int NBLK = 512;         // 2 dirs * 256 blocks

__global__ __launch_bounds__(256) void pack_kernel(
    const float* __restrict__ xyz1, const float* __restrict__ xyz2,
    float4* __restrict__ p1, float4* __restrict__ p2) {
  int i = blockIdx.x * 256 + threadIdx.x;   // [0, 2*BN)
  const float* s = (i < BN) ? xyz1 : xyz2;
  float4* d      = (i < BN) ? p1 : p2;
  int j          = (i < BN) ? i : (i - BN);
  float x = s[3 * j], y = s[3 * j + 1], z = s[3 * j + 2];
  d[j] = make_float4(x, y, z, fmaf(x, x, fmaf(y, y, z * z)));
}

__global__ __launch_bounds__(256) void nn_packed_kernel(
    const float4* __restrict__ p1, const float4* __restrict__ p2,
    float* __restrict__ blocksums) {
  const int bid   = blockIdx.x;     // 0..511
  const int dir   = bid >> 8;       // 0: q from set1 vs set2; 1: swapped
  const int idx   = bid & 255;
  const int b     = idx >> 5;       // 32 blocks of 256 queries per batch
  const int chunk = idx & 31;
  const float4* __restrict__ q = (dir ? p2 : p1) + b * N + chunk * 256;
  const float4* __restrict__ t = (dir ? p1 : p2) + b * N;

  float4 qv = q[threadIdx.x];
  const float qx = -2.0f * qv.x, qy = -2.0f * qv.y, qz = -2.0f * qv.z;

  float mn0 = 3.4e38f, mn1 = 3.4e38f, mn2 = 3.4e38f, mn3 = 3.4e38f;
  #pragma unroll 2
  for (int m = 0; m < N; m += 4) {           // m is wave-uniform -> s_load
    float4 t0 = t[m + 0], t1 = t[m + 1], t2 = t[m + 2], t3 = t[m + 3];
    float d0 = fmaf(qx, t0.x, fmaf(qy, t0.y, fmaf(qz, t0.z, t0.w)));
    float d1 = fmaf(qx, t1.x, fmaf(qy, t1.y, fmaf(qz, t1.z, t1.w)));
    float d2 = fmaf(qx, t2.x, fmaf(qy, t2.y, fmaf(qz, t2.z, t2.w)));
    float d3 = fmaf(qx, t3.x, fmaf(qy, t3.y, fmaf(qz, t3.z, t3.w)));
    mn0 = fminf(mn0, d0); mn1 = fminf(mn1, d1);
    mn2 = fminf(mn2, d2); mn3 = fminf(mn3, d3);
  }
  float v = qv.w + fminf(fminf(mn0, mn1), fminf(mn2, mn3));

  // deterministic block sum
  #pragma unroll
  for (int off = 32; off > 0; off >>= 1) v += __shfl_down(v, off);
  __shared__ float ssum[4];
  const int lane = threadIdx.x & 63, wid = threadIdx.x >> 6;
  if (lane == 0) ssum[wid] = v;
  __syncthreads();
  if (threadIdx.x == 0)
    blocksums[bid] = ssum[0] + ssum[1] + ssum[2] + ssum[3];
}

__global__ __launch_bounds__(512) void finalize_sums_kernel(
    const float* __restrict__ blocksums, float* __restrict__ out) {
  float v = blocksums[threadIdx.x];
  #pragma unroll
  for (int off = 32; off > 0; off >>= 1) v += __shfl_down(v, off);
  __shared__ float ssum[8];
  const int lane = threadIdx.x & 63, wid = threadIdx.x >> 6;
  if (lane == 0) ssum[wid] = v;
  __syncthreads();
  if (threadIdx.x == 0) {
    float s = 0.f;
    #pragma unroll
    for (int w = 0; w < 8; ++w) s += ssum[w];
    out[0] = s * (1.0f / 65536.0f);   // mean1 + mean2, since B*N == B*M
  }
}

// ---------- fallback path (only if ws_size is unexpectedly tiny) ----------
__global__ void zero_out_kernel(float* out) { out[0] = 0.f; }

__global__ __launch_bounds__(256) void nn_raw_kernel(
    const float* __restrict__ xyz1, const float* __restrict__ xyz2,
    float* __restrict__ out) {
  const int bid   = blockIdx.x;
  const int dir   = bid >> 8;
  const int idx   = bid & 255;
  const int b     = idx >> 5;
  const int chunk = idx & 31;
  const float* __restrict__ q =
      (dir ? xyz2 : xyz1) + (size_t)b * N * 3 + (size_t)chunk * 256 * 3;
  const float* __restrict__ t = (dir ? xyz1 : xyz2) + (size_t)b * N * 3;
  float qx = q[threadIdx.x * 3], qy = q[threadIdx.x * 3 + 1],
        qz = q[threadIdx.x * 3 + 2];
  float mn0 = 3.4e38f, mn1 = 3.4e38f;
  for (int m = 0; m < N; m += 2) {
    float ax = t[3 * m + 0], ay = t[3 * m + 1], az = t[3 * m + 2];
    float bx = t[3 * m + 3], by = t[3 * m + 4], bz = t[3 * m + 5];
    float dx = qx - ax, dy = qy - ay, dz = qz - az;
    float d0 = fmaf(dx, dx, fmaf(dy, dy, dz * dz));
    dx = qx - bx; dy = qy - by; dz = qz - bz;
    float d1 = fmaf(dx, dx, fmaf(dy, dy, dz * dz));
    mn0 = fminf(mn0, d0); mn1 = fminf(mn1, d1);
  }
  float v = fminf(mn0, mn1);
  #pragma unroll
  for (int off = 32; off > 0; off >>= 1) v += __shfl_down(v, off);
  __shared__ float ssum[4];
  const int lane = threadIdx.x & 63, wid = threadIdx.x >> 6;
  if (lane == 0) ssum[wid] = v;
  __syncthreads();
  if (threadIdx.x == 0) atomicAdd(out, ssum[0] + ssum[1] + ssum[2] + ssum[3]);
}

__global__ void finalize_scale_kernel(float* out) {
  out[0] *= (1.0f / 65536.0f);
}

extern "C" void kernel_launch(void* const* d_in, const int* in_sizes, int n_in,
                              void* d_out, int out_size, void* d_ws, size_t ws_size,
                              hipStream_t stream) {
  const float* xyz1 = (const float*)d_in[0];
  const float* xyz2 = (const float*)d_in[1];
  float* out = (float*)d_out;

  const size_t need = (size_t)2 * BN * sizeof(float4) + NBLK * sizeof(float);
  if (ws_size >= need) {
    float4* p1 = (float4*)d_ws;
    float4* p2 = p1 + BN;
    float* blocksums = (float*)(p2 + BN);
    pack_kernel<<<(2 * BN) / 256, 256, 0, stream>>>(xyz1, xyz2, p1, p2);
    nn_packed_kernel<<<NBLK, 256, 0, stream>>>(p1, p2, blocksums);
    finalize_sums_kernel<<<1, NBLK, 0, stream>>>(blocksums, out);
  } else {
    zero_out_kernel<<<1, 1, 0, stream>>>(out);
    nn_raw_kernel<<<NBLK, 256, 0, stream>>>(xyz1, xyz2, out);
    finalize_scale_kernel<<<1, 1, 0, stream>>>(out);
  }
}

// Round 2
// 125.300 us; speedup vs baseline: 2.6264x; 2.6264x over previous
//
#include <hip/hip_runtime.h>

// Chamfer distance L2: B=8, N=M=8192, fp32 3D points.
// d(q,p) = ||q||^2 + ||p||^2 - 2 q.p  (matches reference's expanded form).
// Pack each set as float4 (x, y, z, ||p||^2); per-thread q' = -2q.
// Round 2: latency-bound fix — T=16 target chunks (2048 blocks -> 8 waves/SIMD)
// and Q=4 queries/thread (16 independent fma chains per 4-target group).
// Partial mins to ws, reduced in a second pass. Deterministic reductions.

constexpr int B  = 8;
constexpr int N  = 8192;          // points per batch (both sets)
constexpr int BN = B * N;         // 65536 points per set
constexpr int NQ = 2 * BN;        // 131072 total queries (both directions)

__global__ __launch_bounds__(256) void pack_kernel(
    const float* __restrict__ xyz1, const float* __restrict__ xyz2,
    float4* __restrict__ p1, float4* __restrict__ p2) {
  int i = blockIdx.x * 256 + threadIdx.x;   // [0, 2*BN)
  const float* s = (i < BN) ? xyz1 : xyz2;
  float4* d      = (i < BN) ? p1 : p2;
  int j          = (i < BN) ? i : (i - BN);
  float x = s[3 * j], y = s[3 * j + 1], z = s[3 * j + 2];
  d[j] = make_float4(x, y, z, fmaf(x, x, fmaf(y, y, z * z)));
}

// grid = 2(dir) * 8(batch) * 8(query group of 1024) * T(chunks)
// each thread: 4 queries (tid, tid+256, tid+512, tid+768), min over CHUNK targets
template <int CHUNK>
__global__ __launch_bounds__(256, 8) void nn_split_kernel(
    const float4* __restrict__ p1, const float4* __restrict__ p2,
    float* __restrict__ pmin) {
  constexpr int T = N / CHUNK;
  int bid  = blockIdx.x;
  int c    = bid % T;
  int rest = bid / T;
  int qg   = rest & 7;
  rest >>= 3;
  int b    = rest & 7;
  int dir  = rest >> 3;

  const float4* __restrict__ q = (dir ? p2 : p1) + b * N + qg * 1024;
  const float4* __restrict__ t = (dir ? p1 : p2) + b * N + c * CHUNK;

  float qx[4], qy[4], qz[4];
  #pragma unroll
  for (int i = 0; i < 4; ++i) {
    float4 qv = q[threadIdx.x + i * 256];
    qx[i] = -2.0f * qv.x; qy[i] = -2.0f * qv.y; qz[i] = -2.0f * qv.z;
  }

  float mn[4][4];
  #pragma unroll
  for (int i = 0; i < 4; ++i)
    #pragma unroll
    for (int s = 0; s < 4; ++s) mn[i][s] = 3.4e38f;

  for (int m = 0; m < CHUNK; m += 4) {       // m wave-uniform -> scalar loads
    float4 t0 = t[m + 0], t1 = t[m + 1], t2 = t[m + 2], t3 = t[m + 3];
    #pragma unroll
    for (int i = 0; i < 4; ++i) {
      float d0 = fmaf(qx[i], t0.x, fmaf(qy[i], t0.y, fmaf(qz[i], t0.z, t0.w)));
      float d1 = fmaf(qx[i], t1.x, fmaf(qy[i], t1.y, fmaf(qz[i], t1.z, t1.w)));
      float d2 = fmaf(qx[i], t2.x, fmaf(qy[i], t2.y, fmaf(qz[i], t2.z, t2.w)));
      float d3 = fmaf(qx[i], t3.x, fmaf(qy[i], t3.y, fmaf(qz[i], t3.z, t3.w)));
      mn[i][0] = fminf(mn[i][0], d0); mn[i][1] = fminf(mn[i][1], d1);
      mn[i][2] = fminf(mn[i][2], d2); mn[i][3] = fminf(mn[i][3], d3);
    }
  }

  // pmin layout: [c][dir*65536 + b*8192 + qg*1024 + i*256 + tid] (coalesced)
  const size_t base = (size_t)c * NQ + (size_t)dir * BN + b * N + qg * 1024;
  #pragma unroll
  for (int i = 0; i < 4; ++i) {
    float v = fminf(fminf(mn[i][0], mn[i][1]), fminf(mn[i][2], mn[i][3]));
    pmin[base + i * 256 + threadIdx.x] = v;
  }
}

template <int T>
__global__ __launch_bounds__(256) void reduce_min_kernel(
    const float* __restrict__ pmin, const float4* __restrict__ p1,
    const float4* __restrict__ p2, float* __restrict__ blocksums) {
  int gq = blockIdx.x * 256 + threadIdx.x;   // [0, NQ)
  float v = 3.4e38f;
  #pragma unroll
  for (int c = 0; c < T; ++c) v = fminf(v, pmin[(size_t)c * NQ + gq]);
  int dir = gq >> 16, idx = gq & (BN - 1);
  v += (dir ? p2 : p1)[idx].w;               // add ||q||^2 here

  #pragma unroll
  for (int off = 32; off > 0; off >>= 1) v += __shfl_down(v, off);
  __shared__ float ssum[4];
  const int lane = threadIdx.x & 63, wid = threadIdx.x >> 6;
  if (lane == 0) ssum[wid] = v;
  __syncthreads();
  if (threadIdx.x == 0)
    blocksums[blockIdx.x] = ssum[0] + ssum[1] + ssum[2] + ssum[3];
}

__global__ __launch_bounds__(512) void finalize_sums_kernel(
    const float* __restrict__ blocksums, float* __restrict__ out) {
  float v = blocksums[threadIdx.x];
  #pragma unroll
  for (int off = 32; off > 0; off >>= 1) v += __shfl_down(v, off);
  __shared__ float ssum[8];
  const int lane = threadIdx.x & 63, wid = threadIdx.x >> 6;
  if (lane == 0) ssum[wid] = v;
  __syncthreads();
  if (threadIdx.x == 0) {
    float s = 0.f;
    #pragma unroll
    for (int w = 0; w < 8; ++w) s += ssum[w];
    out[0] = s * (1.0f / 65536.0f);   // mean1 + mean2 (B*N == B*M)
  }
}

// ---------- round-1 proven path (fallback if ws too small for pmin) --------
__global__ __launch_bounds__(256) void nn_packed_kernel(
    const float4* __restrict__ p1, const float4* __restrict__ p2,
    float* __restrict__ blocksums) {
  const int bid   = blockIdx.x;     // 0..511
  const int dir   = bid >> 8;
  const int idx   = bid & 255;
  const int b     = idx >> 5;
  const int chunk = idx & 31;
  const float4* __restrict__ q = (dir ? p2 : p1) + b * N + chunk * 256;
  const float4* __restrict__ t = (dir ? p1 : p2) + b * N;

  float4 qv = q[threadIdx.x];
  const float qx = -2.0f * qv.x, qy = -2.0f * qv.y, qz = -2.0f * qv.z;

  float mn0 = 3.4e38f, mn1 = 3.4e38f, mn2 = 3.4e38f, mn3 = 3.4e38f;
  #pragma unroll 2
  for (int m = 0; m < N; m += 4) {
    float4 t0 = t[m + 0], t1 = t[m + 1], t2 = t[m + 2], t3 = t[m + 3];
    float d0 = fmaf(qx, t0.x, fmaf(qy, t0.y, fmaf(qz, t0.z, t0.w)));
    float d1 = fmaf(qx, t1.x, fmaf(qy, t1.y, fmaf(qz, t1.z, t1.w)));
    float d2 = fmaf(qx, t2.x, fmaf(qy, t2.y, fmaf(qz, t2.z, t2.w)));
    float d3 = fmaf(qx, t3.x, fmaf(qy, t3.y, fmaf(qz, t3.z, t3.w)));
    mn0 = fminf(mn0, d0); mn1 = fminf(mn1, d1);
    mn2 = fminf(mn2, d2); mn3 = fminf(mn3, d3);
  }
  float v = qv.w + fminf(fminf(mn0, mn1), fminf(mn2, mn3));

  #pragma unroll
  for (int off = 32; off > 0; off >>= 1) v += __shfl_down(v, off);
  __shared__ float ssum[4];
  const int lane = threadIdx.x & 63, wid = threadIdx.x >> 6;
  if (lane == 0) ssum[wid] = v;
  __syncthreads();
  if (threadIdx.x == 0)
    blocksums[bid] = ssum[0] + ssum[1] + ssum[2] + ssum[3];
}

extern "C" void kernel_launch(void* const* d_in, const int* in_sizes, int n_in,
                              void* d_out, int out_size, void* d_ws, size_t ws_size,
                              hipStream_t stream) {
  const float* xyz1 = (const float*)d_in[0];
  const float* xyz2 = (const float*)d_in[1];
  float* out = (float*)d_out;

  float4* p1 = (float4*)d_ws;
  float4* p2 = p1 + BN;
  float*  after_pack = (float*)(p2 + BN);
  const size_t pack_bytes = (size_t)2 * BN * sizeof(float4);

  const size_t need16 = pack_bytes + (size_t)16 * NQ * sizeof(float) + 512 * sizeof(float);
  const size_t need8  = pack_bytes + (size_t)8  * NQ * sizeof(float) + 512 * sizeof(float);
  const size_t need1  = pack_bytes + 512 * sizeof(float);

  if (ws_size >= need8) {
    pack_kernel<<<(2 * BN) / 256, 256, 0, stream>>>(xyz1, xyz2, p1, p2);
    if (ws_size >= need16) {
      constexpr int T = 16;
      float* pmin = after_pack;
      float* blocksums = pmin + (size_t)T * NQ;
      nn_split_kernel<N / T><<<2 * 8 * 8 * T, 256, 0, stream>>>(p1, p2, pmin);
      reduce_min_kernel<T><<<NQ / 256, 256, 0, stream>>>(pmin, p1, p2, blocksums);
      finalize_sums_kernel<<<1, 512, 0, stream>>>(blocksums, out);
    } else {
      constexpr int T = 8;
      float* pmin = after_pack;
      float* blocksums = pmin + (size_t)T * NQ;
      nn_split_kernel<N / T><<<2 * 8 * 8 * T, 256, 0, stream>>>(p1, p2, pmin);
      reduce_min_kernel<T><<<NQ / 256, 256, 0, stream>>>(pmin, p1, p2, blocksums);
      finalize_sums_kernel<<<1, 512, 0, stream>>>(blocksums, out);
    }
  } else if (ws_size >= need1) {
    float* blocksums = after_pack;
    pack_kernel<<<(2 * BN) / 256, 256, 0, stream>>>(xyz1, xyz2, p1, p2);
    nn_packed_kernel<<<512, 256, 0, stream>>>(p1, p2, blocksums);
    finalize_sums_kernel<<<1, 512, 0, stream>>>(blocksums, out);
  }
}

// Round 3
// 95.797 us; speedup vs baseline: 3.4352x; 1.3080x over previous
//
#include <hip/hip_runtime.h>

// Chamfer distance L2: B=8, N=M=8192, fp32 3D points.
// d(q,p) = ||q||^2 + ||p||^2 - 2 q.p  (reference's expanded form).
// R3: packed-fp32 math. Targets in SoA (X,Y,Z,W arrays), staged per-chunk in
// LDS; inner loop uses v_pk_fma_f32 (2 distances / 3 instrs) + v_min3_f32
// (1 instr folds both into the accumulator) -> ~2 VALU instrs per pair.
// All operands VGPR (LDS broadcast reads), so no SGPR-limit v_movs.

typedef float v2f __attribute__((ext_vector_type(2)));
typedef float v4f __attribute__((ext_vector_type(4)));

constexpr int B  = 8;
constexpr int N  = 8192;          // points per batch per set
constexpr int BN = B * N;         // 65536 points per set
constexpr int NQ = 2 * BN;        // 131072 queries (both directions)

// SoA pack: per set layout [X(BN) | Y(BN) | Z(BN) | W(BN)], W = ||p||^2
__global__ __launch_bounds__(256) void pack_soa_kernel(
    const float* __restrict__ xyz1, const float* __restrict__ xyz2,
    float* __restrict__ s1, float* __restrict__ s2) {
  int i = blockIdx.x * 256 + threadIdx.x;   // [0, 2*BN)
  const float* src = (i < BN) ? xyz1 : xyz2;
  float* dst       = (i < BN) ? s1 : s2;
  int j            = (i < BN) ? i : i - BN;
  float x = src[3 * j], y = src[3 * j + 1], z = src[3 * j + 2];
  dst[j]          = x;
  dst[j + BN]     = y;
  dst[j + 2 * BN] = z;
  dst[j + 3 * BN] = fmaf(x, x, fmaf(y, y, z * z));
}

// grid = 2(dir) * 8(batch) * 8(query group of 1024) * T(chunks of N/T targets)
template <int T>
__global__ __launch_bounds__(256, 6) void nn_pk_kernel(
    const float* __restrict__ s1, const float* __restrict__ s2,
    float* __restrict__ pmin) {
  constexpr int CHUNK = N / T;
  int bid  = blockIdx.x;
  int c    = bid % T;
  int rest = bid / T;
  int qg   = rest & 7;
  rest >>= 3;
  int b    = rest & 7;
  int dir  = rest >> 3;

  const float* __restrict__ qs = dir ? s2 : s1;
  const float* __restrict__ ts = dir ? s1 : s2;
  const int qoff = b * N + qg * 1024;
  const int toff = b * N + c * CHUNK;

  // stage chunk into LDS, SoA
  __shared__ __align__(16) float lds[4][CHUNK];
  #pragma unroll
  for (int a = 0; a < 4; ++a) {
    #pragma unroll
    for (int r = 0; r < CHUNK / 512; ++r) {
      int e = r * 512 + 2 * threadIdx.x;
      float2 v = *(const float2*)(ts + a * BN + toff + e);
      *(float2*)(&lds[a][e]) = v;
    }
  }
  __syncthreads();

  // 4 queries per thread; q' = -2q broadcast into packed pairs
  v2f qx2[4], qy2[4], qz2[4];
  float qw[4];
  #pragma unroll
  for (int i = 0; i < 4; ++i) {
    int qi = qoff + threadIdx.x + i * 256;
    float qx = -2.0f * qs[qi];
    float qy = -2.0f * qs[qi + BN];
    float qz = -2.0f * qs[qi + 2 * BN];
    qx2[i].x = qx; qx2[i].y = qx;
    qy2[i].x = qy; qy2[i].y = qy;
    qz2[i].x = qz; qz2[i].y = qz;
    (void)qw[i];
  }

  float acc[4][2];
  #pragma unroll
  for (int i = 0; i < 4; ++i) { acc[i][0] = 3.4e38f; acc[i][1] = 3.4e38f; }

  for (int m = 0; m < CHUNK; m += 4) {
    v4f xs = *(const v4f*)(&lds[0][m]);   // uniform addr -> broadcast b128
    v4f ys = *(const v4f*)(&lds[1][m]);
    v4f zs = *(const v4f*)(&lds[2][m]);
    v4f wv = *(const v4f*)(&lds[3][m]);
    #pragma unroll
    for (int p = 0; p < 2; ++p) {
      v2f tx = p ? xs.zw : xs.xy;
      v2f ty = p ? ys.zw : ys.xy;
      v2f tz = p ? zs.zw : zs.xy;
      v2f tw = p ? wv.zw : wv.xy;
      #pragma unroll
      for (int i = 0; i < 4; ++i) {
        v2f d;
        asm("v_pk_fma_f32 %0, %1, %2, %3\n\t"
            "v_pk_fma_f32 %0, %4, %5, %0\n\t"
            "v_pk_fma_f32 %0, %6, %7, %0"
            : "=&v"(d)
            : "v"(qz2[i]), "v"(tz), "v"(tw),
              "v"(qy2[i]), "v"(ty),
              "v"(qx2[i]), "v"(tx));
        asm("v_min3_f32 %0, %0, %1, %2"
            : "+v"(acc[i][p])
            : "v"(d.x), "v"(d.y));
      }
    }
  }

  // pmin layout: [c][dir*BN + b*N + qg*1024 + i*256 + tid] (coalesced)
  const size_t base = (size_t)c * NQ + (size_t)dir * BN + b * N + qg * 1024;
  #pragma unroll
  for (int i = 0; i < 4; ++i)
    pmin[base + i * 256 + threadIdx.x] = fminf(acc[i][0], acc[i][1]);
}

template <int T>
__global__ __launch_bounds__(256) void reduce_min_kernel(
    const float* __restrict__ pmin, const float* __restrict__ s1,
    const float* __restrict__ s2, float* __restrict__ blocksums) {
  int gq = blockIdx.x * 256 + threadIdx.x;   // [0, NQ)
  float v = 3.4e38f;
  #pragma unroll
  for (int c = 0; c < T; ++c) v = fminf(v, pmin[(size_t)c * NQ + gq]);
  int dir = gq >> 16, idx = gq & (BN - 1);
  v += (dir ? s2 : s1)[3 * BN + idx];        // + ||q||^2

  #pragma unroll
  for (int off = 32; off > 0; off >>= 1) v += __shfl_down(v, off);
  __shared__ float ssum[4];
  const int lane = threadIdx.x & 63, wid = threadIdx.x >> 6;
  if (lane == 0) ssum[wid] = v;
  __syncthreads();
  if (threadIdx.x == 0)
    blocksums[blockIdx.x] = ssum[0] + ssum[1] + ssum[2] + ssum[3];
}

__global__ __launch_bounds__(512) void finalize_sums_kernel(
    const float* __restrict__ blocksums, float* __restrict__ out) {
  float v = blocksums[threadIdx.x];
  #pragma unroll
  for (int off = 32; off > 0; off >>= 1) v += __shfl_down(v, off);
  __shared__ float ssum[8];
  const int lane = threadIdx.x & 63, wid = threadIdx.x >> 6;
  if (lane == 0) ssum[wid] = v;
  __syncthreads();
  if (threadIdx.x == 0) {
    float s = 0.f;
    #pragma unroll
    for (int w = 0; w < 8; ++w) s += ssum[w];
    out[0] = s * (1.0f / 65536.0f);   // mean1 + mean2 (B*N == B*M)
  }
}

// ---------- round-1 proven fallback (if ws too small for pmin) ----------
__global__ __launch_bounds__(256) void pack4_kernel(
    const float* __restrict__ xyz1, const float* __restrict__ xyz2,
    float4* __restrict__ p1, float4* __restrict__ p2) {
  int i = blockIdx.x * 256 + threadIdx.x;
  const float* s = (i < BN) ? xyz1 : xyz2;
  float4* d      = (i < BN) ? p1 : p2;
  int j          = (i < BN) ? i : (i - BN);
  float x = s[3 * j], y = s[3 * j + 1], z = s[3 * j + 2];
  d[j] = make_float4(x, y, z, fmaf(x, x, fmaf(y, y, z * z)));
}

__global__ __launch_bounds__(256) void nn_packed_kernel(
    const float4* __restrict__ p1, const float4* __restrict__ p2,
    float* __restrict__ blocksums) {
  const int bid   = blockIdx.x;
  const int dir   = bid >> 8;
  const int idx   = bid & 255;
  const int b     = idx >> 5;
  const int chunk = idx & 31;
  const float4* __restrict__ q = (dir ? p2 : p1) + b * N + chunk * 256;
  const float4* __restrict__ t = (dir ? p1 : p2) + b * N;

  float4 qv = q[threadIdx.x];
  const float qx = -2.0f * qv.x, qy = -2.0f * qv.y, qz = -2.0f * qv.z;

  float mn0 = 3.4e38f, mn1 = 3.4e38f, mn2 = 3.4e38f, mn3 = 3.4e38f;
  #pragma unroll 2
  for (int m = 0; m < N; m += 4) {
    float4 t0 = t[m + 0], t1 = t[m + 1], t2 = t[m + 2], t3 = t[m + 3];
    float d0 = fmaf(qx, t0.x, fmaf(qy, t0.y, fmaf(qz, t0.z, t0.w)));
    float d1 = fmaf(qx, t1.x, fmaf(qy, t1.y, fmaf(qz, t1.z, t1.w)));
    float d2 = fmaf(qx, t2.x, fmaf(qy, t2.y, fmaf(qz, t2.z, t2.w)));
    float d3 = fmaf(qx, t3.x, fmaf(qy, t3.y, fmaf(qz, t3.z, t3.w)));
    mn0 = fminf(mn0, d0); mn1 = fminf(mn1, d1);
    mn2 = fminf(mn2, d2); mn3 = fminf(mn3, d3);
  }
  float v = qv.w + fminf(fminf(mn0, mn1), fminf(mn2, mn3));

  #pragma unroll
  for (int off = 32; off > 0; off >>= 1) v += __shfl_down(v, off);
  __shared__ float ssum[4];
  const int lane = threadIdx.x & 63, wid = threadIdx.x >> 6;
  if (lane == 0) ssum[wid] = v;
  __syncthreads();
  if (threadIdx.x == 0)
    blocksums[bid] = ssum[0] + ssum[1] + ssum[2] + ssum[3];
}

extern "C" void kernel_launch(void* const* d_in, const int* in_sizes, int n_in,
                              void* d_out, int out_size, void* d_ws, size_t ws_size,
                              hipStream_t stream) {
  const float* xyz1 = (const float*)d_in[0];
  const float* xyz2 = (const float*)d_in[1];
  float* out = (float*)d_out;

  float* s1 = (float*)d_ws;                 // 4*BN floats
  float* s2 = s1 + 4 * BN;                  // 4*BN floats
  float* after_pack = s2 + 4 * BN;
  const size_t pack_bytes = (size_t)8 * BN * sizeof(float);

  const size_t need16 = pack_bytes + (size_t)16 * NQ * sizeof(float) + 512 * sizeof(float);
  const size_t need8  = pack_bytes + (size_t)8  * NQ * sizeof(float) + 512 * sizeof(float);
  const size_t need1  = (size_t)2 * BN * sizeof(float4) + 512 * sizeof(float);

  if (ws_size >= need8) {
    pack_soa_kernel<<<(2 * BN) / 256, 256, 0, stream>>>(xyz1, xyz2, s1, s2);
    if (ws_size >= need16) {
      constexpr int T = 16;
      float* pmin = after_pack;
      float* blocksums = pmin + (size_t)T * NQ;
      nn_pk_kernel<T><<<2 * 8 * 8 * T, 256, 0, stream>>>(s1, s2, pmin);
      reduce_min_kernel<T><<<NQ / 256, 256, 0, stream>>>(pmin, s1, s2, blocksums);
      finalize_sums_kernel<<<1, 512, 0, stream>>>(blocksums, out);
    } else {
      constexpr int T = 8;
      float* pmin = after_pack;
      float* blocksums = pmin + (size_t)T * NQ;
      nn_pk_kernel<T><<<2 * 8 * 8 * T, 256, 0, stream>>>(s1, s2, pmin);
      reduce_min_kernel<T><<<NQ / 256, 256, 0, stream>>>(pmin, s1, s2, blocksums);
      finalize_sums_kernel<<<1, 512, 0, stream>>>(blocksums, out);
    }
  } else if (ws_size >= need1) {
    float4* p1 = (float4*)d_ws;
    float4* p2 = p1 + BN;
    float* blocksums = (float*)(p2 + BN);
    pack4_kernel<<<(2 * BN) / 256, 256, 0, stream>>>(xyz1, xyz2, p1, p2);
    nn_packed_kernel<<<512, 256, 0, stream>>>(p1, p2, blocksums);
    finalize_sums_kernel<<<1, 512, 0, stream>>>(blocksums, out);
  }
}

// Round 4
// 89.925 us; speedup vs baseline: 3.6596x; 1.0653x over previous
//
#include <hip/hip_runtime.h>

// Chamfer distance L2: B=8, N=M=8192, fp32 3D points.
// d(q,p) = ||q||^2 + ||p||^2 - 2 q.p  (reference's expanded form).
// R4: R3 was LDS-return-pipe-bound (4x broadcast ds_read_b128 / 4 targets
// ~= 12cyc each on the per-CU LDS pipe => ~82us, measured 87us).
// Fix: feed targets via the idle SMEM pipe. Targets in grouped-SoA
// (4 points = [4x|4y|4z|4w] = 64B) so uniform loads become s_load_dwordx16;
// v_pk_fma_f32 takes the target pair directly as its single allowed SGPR
// source. Q=8 queries/thread: 68 VALU / 32 pairs ~= 2.1 instr/pair, 0 LDS.
// Cross-chunk min via atomicMin on order-preserving uint keys (exact,
// order-independent); pmin is 0.5MB instead of 16.8MB.

typedef float v2f __attribute__((ext_vector_type(2)));

constexpr int B  = 8;
constexpr int N  = 8192;
constexpr int BN = B * N;         // 65536 points per set
constexpr int NQ = 2 * BN;        // 131072 queries (both directions)
constexpr int T  = 32;            // target chunks per batch
constexpr int CHUNK = N / T;      // 256 targets per chunk
constexpr int Q  = 8;             // queries per thread
constexpr int QPB = 256 * Q;      // 2048 queries per block
constexpr int NQG = N / QPB;      // 4 query groups per batch

// SoA [X|Y|Z|W] (for query loads + finalize) and grouped-SoA (for targets)
__global__ __launch_bounds__(256) void pack2_kernel(
    const float* __restrict__ xyz1, const float* __restrict__ xyz2,
    float* __restrict__ soa1, float* __restrict__ soa2,
    float* __restrict__ g1, float* __restrict__ g2) {
  int i = blockIdx.x * 256 + threadIdx.x;   // [0, 2*BN)
  const float* src = (i < BN) ? xyz1 : xyz2;
  float* soa       = (i < BN) ? soa1 : soa2;
  float* gg        = (i < BN) ? g1 : g2;
  int j            = (i < BN) ? i : i - BN;
  float x = src[3 * j], y = src[3 * j + 1], z = src[3 * j + 2];
  float w = fmaf(x, x, fmaf(y, y, z * z));
  soa[j]          = x;
  soa[j + BN]     = y;
  soa[j + 2 * BN] = z;
  soa[j + 3 * BN] = w;
  float* G = gg + (j >> 2) * 16;
  int r = j & 3;
  G[r] = x; G[r + 4] = y; G[r + 8] = z; G[r + 12] = w;
}

// grid = 2(dir) * 8(batch) * 32(chunk) * 4(query group); qg fastest so
// consecutive blocks share the target stream (scalar-cache friendly).
__global__ __launch_bounds__(256, 5) void nn_spk_kernel(
    const float* __restrict__ soa1, const float* __restrict__ soa2,
    const float* __restrict__ g1, const float* __restrict__ g2,
    unsigned int* __restrict__ pmin) {
  int bid = blockIdx.x;
  int qg  = bid & 3;
  int c   = (bid >> 2) & 31;
  int b   = (bid >> 7) & 7;
  int dir = (bid >> 10) & 1;

  const float* __restrict__ qs = dir ? soa2 : soa1;
  const float* __restrict__ tp =
      (dir ? g1 : g2) + ((size_t)(b * N + c * CHUNK) >> 2) * 16;
  const int qbase = b * N + qg * QPB;

  // per-thread queries, q' = -2q broadcast into packed pairs
  v2f qx2[Q], qy2[Q], qz2[Q];
  #pragma unroll
  for (int i = 0; i < Q; ++i) {
    int qi = qbase + threadIdx.x + i * 256;
    float qx = -2.0f * qs[qi];
    float qy = -2.0f * qs[qi + BN];
    float qz = -2.0f * qs[qi + 2 * BN];
    qx2[i].x = qx; qx2[i].y = qx;
    qy2[i].x = qy; qy2[i].y = qy;
    qz2[i].x = qz; qz2[i].y = qz;
  }

  float acc[Q][2];
  #pragma unroll
  for (int i = 0; i < Q; ++i) { acc[i][0] = 3.4e38f; acc[i][1] = 3.4e38f; }

  #pragma unroll 2
  for (int g = 0; g < CHUNK / 4; ++g) {
    const float* gp = tp + g * 16;          // uniform -> s_load
    v2f tx01 = *(const v2f*)(gp +  0), tx23 = *(const v2f*)(gp +  2);
    v2f ty01 = *(const v2f*)(gp +  4), ty23 = *(const v2f*)(gp +  6);
    v2f tz01 = *(const v2f*)(gp +  8), tz23 = *(const v2f*)(gp + 10);
    v2f tw01 = *(const v2f*)(gp + 12), tw23 = *(const v2f*)(gp + 14);
    #pragma unroll
    for (int i = 0; i < Q; ++i) {
      v2f d0, d1;
      asm("v_pk_fma_f32 %0, %1, %2, %3\n\t"
          "v_pk_fma_f32 %0, %4, %5, %0\n\t"
          "v_pk_fma_f32 %0, %6, %7, %0"
          : "=&v"(d0)
          : "v"(qz2[i]), "s"(tz01), "v"(tw01),
            "v"(qy2[i]), "s"(ty01),
            "v"(qx2[i]), "s"(tx01));
      asm("v_min3_f32 %0, %0, %1, %2"
          : "+v"(acc[i][0]) : "v"(d0.x), "v"(d0.y));
      asm("v_pk_fma_f32 %0, %1, %2, %3\n\t"
          "v_pk_fma_f32 %0, %4, %5, %0\n\t"
          "v_pk_fma_f32 %0, %6, %7, %0"
          : "=&v"(d1)
          : "v"(qz2[i]), "s"(tz23), "v"(tw23),
            "v"(qy2[i]), "s"(ty23),
            "v"(qx2[i]), "s"(tx23));
      asm("v_min3_f32 %0, %0, %1, %2"
          : "+v"(acc[i][1]) : "v"(d1.x), "v"(d1.y));
    }
  }

  // order-preserving uint key; atomic min (exact, order-independent)
  #pragma unroll
  for (int i = 0; i < Q; ++i) {
    float f = fminf(acc[i][0], acc[i][1]);
    unsigned int u = __float_as_uint(f);
    u = (u & 0x80000000u) ? ~u : (u | 0x80000000u);
    atomicMin(&pmin[dir * BN + qbase + threadIdx.x + i * 256], u);
  }
}

__global__ __launch_bounds__(256) void reduce_final_kernel(
    const unsigned int* __restrict__ pmin, const float* __restrict__ soa1,
    const float* __restrict__ soa2, float* __restrict__ blocksums) {
  int gq = blockIdx.x * 256 + threadIdx.x;   // [0, NQ)
  unsigned int u = pmin[gq];
  unsigned int bits = (u & 0x80000000u) ? (u ^ 0x80000000u) : ~u;
  float v = __uint_as_float(bits);
  int dir = gq >> 16, idx = gq & (BN - 1);
  v += (dir ? soa2 : soa1)[3 * BN + idx];     // + ||q||^2

  #pragma unroll
  for (int off = 32; off > 0; off >>= 1) v += __shfl_down(v, off);
  __shared__ float ssum[4];
  const int lane = threadIdx.x & 63, wid = threadIdx.x >> 6;
  if (lane == 0) ssum[wid] = v;
  __syncthreads();
  if (threadIdx.x == 0)
    blocksums[blockIdx.x] = ssum[0] + ssum[1] + ssum[2] + ssum[3];
}

__global__ __launch_bounds__(512) void finalize_sums_kernel(
    const float* __restrict__ blocksums, float* __restrict__ out) {
  float v = blocksums[threadIdx.x];
  #pragma unroll
  for (int off = 32; off > 0; off >>= 1) v += __shfl_down(v, off);
  __shared__ float ssum[8];
  const int lane = threadIdx.x & 63, wid = threadIdx.x >> 6;
  if (lane == 0) ssum[wid] = v;
  __syncthreads();
  if (threadIdx.x == 0) {
    float s = 0.f;
    #pragma unroll
    for (int w = 0; w < 8; ++w) s += ssum[w];
    out[0] = s * (1.0f / 65536.0f);   // mean1 + mean2 (B*N == B*M)
  }
}

// ---------- round-1 proven fallback (if ws too small) ----------
__global__ __launch_bounds__(256) void pack4_kernel(
    const float* __restrict__ xyz1, const float* __restrict__ xyz2,
    float4* __restrict__ p1, float4* __restrict__ p2) {
  int i = blockIdx.x * 256 + threadIdx.x;
  const float* s = (i < BN) ? xyz1 : xyz2;
  float4* d      = (i < BN) ? p1 : p2;
  int j          = (i < BN) ? i : (i - BN);
  float x = s[3 * j], y = s[3 * j + 1], z = s[3 * j + 2];
  d[j] = make_float4(x, y, z, fmaf(x, x, fmaf(y, y, z * z)));
}

__global__ __launch_bounds__(256) void nn_packed_kernel(
    const float4* __restrict__ p1, const float4* __restrict__ p2,
    float* __restrict__ blocksums) {
  const int bid   = blockIdx.x;
  const int dir   = bid >> 8;
  const int idx   = bid & 255;
  const int b     = idx >> 5;
  const int chunk = idx & 31;
  const float4* __restrict__ q = (dir ? p2 : p1) + b * N + chunk * 256;
  const float4* __restrict__ t = (dir ? p1 : p2) + b * N;

  float4 qv = q[threadIdx.x];
  const float qx = -2.0f * qv.x, qy = -2.0f * qv.y, qz = -2.0f * qv.z;

  float mn0 = 3.4e38f, mn1 = 3.4e38f, mn2 = 3.4e38f, mn3 = 3.4e38f;
  #pragma unroll 2
  for (int m = 0; m < N; m += 4) {
    float4 t0 = t[m + 0], t1 = t[m + 1], t2 = t[m + 2], t3 = t[m + 3];
    float d0 = fmaf(qx, t0.x, fmaf(qy, t0.y, fmaf(qz, t0.z, t0.w)));
    float d1 = fmaf(qx, t1.x, fmaf(qy, t1.y, fmaf(qz, t1.z, t1.w)));
    float d2 = fmaf(qx, t2.x, fmaf(qy, t2.y, fmaf(qz, t2.z, t2.w)));
    float d3 = fmaf(qx, t3.x, fmaf(qy, t3.y, fmaf(qz, t3.z, t3.w)));
    mn0 = fminf(mn0, d0); mn1 = fminf(mn1, d1);
    mn2 = fminf(mn2, d2); mn3 = fminf(mn3, d3);
  }
  float v = qv.w + fminf(fminf(mn0, mn1), fminf(mn2, mn3));

  #pragma unroll
  for (int off = 32; off > 0; off >>= 1) v += __shfl_down(v, off);
  __shared__ float ssum[4];
  const int lane = threadIdx.x & 63, wid = threadIdx.x >> 6;
  if (lane == 0) ssum[wid] = v;
  __syncthreads();
  if (threadIdx.x == 0)
    blocksums[bid] = ssum[0] + ssum[1] + ssum[2] + ssum[3];
}

extern "C" void kernel_launch(void* const* d_in, const int* in_sizes, int n_in,
                              void* d_out, int out_size, void* d_ws, size_t ws_size,
                              hipStream_t stream) {
  const float* xyz1 = (const float*)d_in[0];
  const float* xyz2 = (const float*)d_in[1];
  float* out = (float*)d_out;

  // ws: soa1(4BN) soa2(4BN) g1(4BN) g2(4BN) pmin(NQ u32) blocksums(512)
  float* soa1 = (float*)d_ws;
  float* soa2 = soa1 + 4 * BN;
  float* g1   = soa2 + 4 * BN;
  float* g2   = g1 + 4 * BN;
  unsigned int* pmin = (unsigned int*)(g2 + 4 * BN);
  float* blocksums = (float*)(pmin + NQ);
  const size_t need = (size_t)16 * BN * sizeof(float) + (size_t)NQ * 4 +
                      512 * sizeof(float);

  if (ws_size >= need) {
    pack2_kernel<<<(2 * BN) / 256, 256, 0, stream>>>(xyz1, xyz2, soa1, soa2, g1, g2);
    hipMemsetAsync(pmin, 0xFF, (size_t)NQ * 4, stream);
    nn_spk_kernel<<<2 * 8 * T * NQG, 256, 0, stream>>>(soa1, soa2, g1, g2, pmin);
    reduce_final_kernel<<<NQ / 256, 256, 0, stream>>>(pmin, soa1, soa2, blocksums);
    finalize_sums_kernel<<<1, 512, 0, stream>>>(blocksums, out);
  } else {
    float4* p1 = (float4*)d_ws;
    float4* p2 = p1 + BN;
    float* bsum = (float*)(p2 + BN);
    pack4_kernel<<<(2 * BN) / 256, 256, 0, stream>>>(xyz1, xyz2, p1, p2);
    nn_packed_kernel<<<512, 256, 0, stream>>>(p1, p2, bsum);
    finalize_sums_kernel<<<1, 512, 0, stream>>>(bsum, out);
  }
}